// Round 1
// baseline (149.962 us; speedup 1.0000x reference)
//
#include <hip/hip_runtime.h>
#include <math.h>
#include <stdint.h>

// EKF batch step, N independent 5-state filters.
// Exploits A rows 3,4 == 0 => P_ has zero cross blocks, S diagonal,
// K has only 2 nonzeros. Memory-bound: LDS-staged coalesced IO.

#define BLK 256

__global__ __launch_bounds__(BLK, 4) void ekf_kernel(
    const float* __restrict__ xg,     // N*5
    const float* __restrict__ Pg,     // N*25
    const float* __restrict__ ag,     // N*2
    const float* __restrict__ Yg,     // 2*N
    const float* __restrict__ n1,     // 5
    const float* __restrict__ n2s,    // 2
    const float* __restrict__ n2k,    // 2
    const float* __restrict__ gains,  // 2
    const float* __restrict__ og,     // 2
    float* __restrict__ out,          // x_new[5N] | P_new[25N] | K[10N]
    int N)
{
    // LDS layout: [P: 256*25][x: 256*5][K: 256*10] = 10240 floats = 40 KiB
    __shared__ float lds[BLK * 25 + BLK * 5 + BLK * 10];
    float* ldsP = lds;
    float* ldsX = lds + BLK * 25;
    float* ldsK = lds + BLK * 25 + BLK * 5;

    const int tid  = threadIdx.x;
    const int base = blockIdx.x * BLK;
    const int valid = min(BLK, N - base);
    if (valid <= 0) return;

    // ---- Phase 1: cooperative coalesced load of P and x into LDS ----
    {
        const float* gp = Pg + (size_t)base * 25;
        int nf = valid * 25;
        int n4 = nf >> 2;
        const float4* gp4 = (const float4*)gp;   // base*100 B: 16B aligned
        float4* lp4 = (float4*)ldsP;
        for (int k = tid; k < n4; k += BLK) lp4[k] = gp4[k];
        for (int k = (n4 << 2) + tid; k < nf; k += BLK) ldsP[k] = gp[k];

        const float* gx = xg + (size_t)base * 5;
        nf = valid * 5;
        n4 = nf >> 2;
        const float4* gx4 = (const float4*)gx;   // base*20 B: 16B aligned
        float4* lx4 = (float4*)ldsX;
        for (int k = tid; k < n4; k += BLK) lx4[k] = gx4[k];
        for (int k = (n4 << 2) + tid; k < nf; k += BLK) ldsX[k] = gx[k];
    }
    __syncthreads();

    // ---- Phase 2: per-thread compute (reads own LDS slice, writes own) ----
    if (tid < valid) {
        const int i = base + tid;
        const float dt = 0.1f;
        const float fPI = 3.14159265358979323846f;
        const float f2PI = 6.28318530717958647692f;

        float2 ai = ((const float2*)ag)[i];           // coalesced 8B load
        float vel    = gains[0] * ai.x;
        float angvel = gains[1] * ai.y;

        float x0 = ldsX[tid * 5 + 0];
        float x1 = ldsX[tid * 5 + 1];
        float x2 = ldsX[tid * 5 + 2];

        // range_angle: numpy mod semantics = fmodf + sign fix
        float ar = x2 + angvel * dt + fPI;
        float w = fmodf(ar, f2PI);
        if (w < 0.0f) w += f2PI;
        float ang = w - fPI;

        float s, c;
        sincosf(ang, &s, &c);

        float px = fminf(fmaxf(x0 + vel * c * dt, -1.0f), 1.0f);
        float py = fminf(fmaxf(x1 + vel * s * dt, -1.0f), 1.0f);

        float m0 = -vel * s * dt;   // A[0][2]
        float m1 =  vel * c * dt;   // A[1][2]

        // P top-left 3x3
        float p00 = ldsP[tid*25 + 0],  p01 = ldsP[tid*25 + 1],  p02 = ldsP[tid*25 + 2];
        float p10 = ldsP[tid*25 + 5],  p11 = ldsP[tid*25 + 6],  p12 = ldsP[tid*25 + 7];
        float p20 = ldsP[tid*25 + 10], p21 = ldsP[tid*25 + 11], p22 = ldsP[tid*25 + 12];

        // B = Atop * P33 (rows 0,1 add m*row2)
        float b00 = p00 + m0 * p20, b01 = p01 + m0 * p21, b02 = p02 + m0 * p22;
        float b10 = p10 + m1 * p20, b11 = p11 + m1 * p21, b12 = p12 + m1 * p22;
        // T = B * Atopᵀ (cols 0,1 add m*col2)
        float t00 = b00 + m0 * b02, t01 = b01 + m1 * b02, t02 = b02;
        float t10 = b10 + m0 * b12, t11 = b11 + m1 * b12, t12 = b12;
        float t20 = p20 + m0 * p22, t21 = p21 + m1 * p22, t22 = p22;

        float q0 = expf(2.0f * n1[0]);
        float q1 = expf(2.0f * n1[1]);
        float q2 = expf(2.0f * n1[2]);
        float q3 = expf(2.0f * n1[3]);
        float q4 = expf(2.0f * n1[4]);

        t00 += q0; t11 += q1; t22 += q2;

        // symmetrize + EPS
        const float EPS_ = 1e-6f;
        float s01 = 0.5f * (t01 + t10);
        float s02 = 0.5f * (t02 + t20);
        float s12 = 0.5f * (t12 + t21);
        t00 += EPS_; t11 += EPS_; t22 += EPS_;

        float og0 = og[0], og1 = og[1];
        float e2s0 = expf(2.0f * n2s[0]), e2s1 = expf(2.0f * n2s[1]);
        float e2k0 = expf(2.0f * n2k[0]), e2k1 = expf(2.0f * n2k[1]);

        float S00 = q3 * og0 * og0 + vel * vel * e2k0 + e2s0;
        float S11 = q4 * og1 * og1 + angvel * angvel * e2k1 + e2s1;

        float K30 = q3 * og0 / S00;
        float K41 = q4 * og1 / S11;

        float y0 = Yg[i], y1 = Yg[N + i];      // coalesced
        float err0 = y0 - og0 * vel;
        float err1 = y1 - og1 * angvel;

        float xn3 = vel    + K30 * err0;
        float xn4 = angvel + K41 * err1;

        float g3 = 1.0f - K30 * og0;
        float g4 = 1.0f - K41 * og1;
        float Pn33 = g3 * q3 + EPS_;
        float Pn44 = g4 * q4 + EPS_;

        // write x_new
        ldsX[tid*5 + 0] = px;
        ldsX[tid*5 + 1] = py;
        ldsX[tid*5 + 2] = ang;
        ldsX[tid*5 + 3] = xn3;
        ldsX[tid*5 + 4] = xn4;

        // write P_new (row-major 5x5)
        float* pp = ldsP + tid * 25;
        pp[0]  = t00;  pp[1]  = s01;  pp[2]  = s02;  pp[3]  = 0.0f; pp[4]  = 0.0f;
        pp[5]  = s01;  pp[6]  = t11;  pp[7]  = s12;  pp[8]  = 0.0f; pp[9]  = 0.0f;
        pp[10] = s02;  pp[11] = s12;  pp[12] = t22;  pp[13] = 0.0f; pp[14] = 0.0f;
        pp[15] = 0.0f; pp[16] = 0.0f; pp[17] = 0.0f; pp[18] = Pn33; pp[19] = 0.0f;
        pp[20] = 0.0f; pp[21] = 0.0f; pp[22] = 0.0f; pp[23] = 0.0f; pp[24] = Pn44;

        // write K (5x2)
        float* kk = ldsK + tid * 10;
        kk[0] = 0.0f; kk[1] = 0.0f; kk[2] = 0.0f; kk[3] = 0.0f;
        kk[4] = 0.0f; kk[5] = 0.0f;
        kk[6] = K30;  kk[7] = 0.0f;
        kk[8] = 0.0f; kk[9] = K41;
    }
    __syncthreads();

    // ---- Phase 3: cooperative coalesced store of all three outputs ----
    {
        // x_new
        float* gx = out + (size_t)base * 5;
        int nf = valid * 5;
        int n4 = nf >> 2;
        float4* g4 = (float4*)gx;
        const float4* l4 = (const float4*)ldsX;
        for (int k = tid; k < n4; k += BLK) g4[k] = l4[k];
        for (int k = (n4 << 2) + tid; k < nf; k += BLK) gx[k] = ldsX[k];

        // P_new at offset 5N
        float* gp = out + (size_t)5 * N + (size_t)base * 25;
        nf = valid * 25;
        n4 = nf >> 2;
        float4* gp4 = (float4*)gp;
        const float4* lp4 = (const float4*)ldsP;
        for (int k = tid; k < n4; k += BLK) gp4[k] = lp4[k];
        for (int k = (n4 << 2) + tid; k < nf; k += BLK) gp[k] = ldsP[k];

        // K at offset 30N
        float* gk = out + (size_t)30 * N + (size_t)base * 10;
        nf = valid * 10;
        n4 = nf >> 2;
        float4* gk4 = (float4*)gk;
        const float4* lk4 = (const float4*)ldsK;
        for (int k = tid; k < n4; k += BLK) gk4[k] = lk4[k];
        for (int k = (n4 << 2) + tid; k < nf; k += BLK) gk[k] = ldsK[k];
    }
}

extern "C" void kernel_launch(void* const* d_in, const int* in_sizes, int n_in,
                              void* d_out, int out_size, void* d_ws, size_t ws_size,
                              hipStream_t stream) {
    const float* x     = (const float*)d_in[0];
    const float* P     = (const float*)d_in[1];
    const float* a     = (const float*)d_in[2];
    const float* Y     = (const float*)d_in[3];
    const float* n1    = (const float*)d_in[4];
    const float* n2s   = (const float*)d_in[5];
    const float* n2k   = (const float*)d_in[6];
    const float* gains = (const float*)d_in[7];
    const float* og    = (const float*)d_in[8];
    const int N = in_sizes[0] / 5;
    const int grid = (N + BLK - 1) / BLK;
    ekf_kernel<<<grid, BLK, 0, stream>>>(x, P, a, Y, n1, n2s, n2k, gains, og,
                                         (float*)d_out, N);
}